// Round 10
// baseline (240.110 us; speedup 1.0000x reference)
//
#include <hip/hip_runtime.h>
#include <hip/hip_fp16.h>

#define EPSC  1e-4f
#define THETA 0.05f
#define EPB   2048   // edges per block (512 thr = 16 groups x 128 edges)
#define EPG   128    // edges per 32-lane group in main loop

#if defined(__has_builtin)
#  if __has_builtin(__builtin_amdgcn_sdot4)
#    define SDOT4(a, b, c) __builtin_amdgcn_sdot4((int)(a), (int)(b), (c), false)
#  endif
#endif
#ifndef SDOT4
static __device__ __forceinline__ int sdot4_sw(unsigned a, unsigned b, int c) {
    #pragma unroll
    for (int k = 0; k < 4; ++k) {
        int ai = (int)(signed char)(a >> (8 * k));
        int bi = (int)(signed char)(b >> (8 * k));
        c += ai * bi;
    }
    return c;
}
#  define SDOT4(a, b, c) sdot4_sw((a), (b), (c))
#endif

// ws layout:
//   float[0..7] softmax(w), float[8..39] m, float[40] b
//   off_scales: scales f32[N]
//   off_nrm:    nrm    f32[N][8]  (= s^2 * sum q^2 per head)
//   off_q8:     q8     N x 128 B  (int8, per-node scale; head h = bytes 16h..16h+15)
//   off_r16:    r16    N x 256 B  (fp16 residual h - s*q)

__device__ __forceinline__ void write_params(const float* w, const float* r_dist,
                                             const float* b, float* ws) {
    float wm = w[0];
    #pragma unroll
    for (int i = 1; i < 8; ++i) wm = fmaxf(wm, w[i]);
    float e[8]; float s = 0.f;
    #pragma unroll
    for (int i = 0; i < 8; ++i) { e[i] = __expf(w[i] - wm); s += e[i]; }
    float inv = 1.0f / s;
    #pragma unroll
    for (int i = 0; i < 8; ++i) ws[i] = e[i] * inv;
    float acc = 0.f;
    for (int c = 0; c < 32; ++c) {
        acc += fabsf(r_dist[c] + EPSC) + EPSC;
        ws[8 + c] = fmaxf(acc, 0.f);
    }
    ws[40] = b[0];
}

__global__ void param_kernel(const float* __restrict__ w,
                             const float* __restrict__ r_dist,
                             const float* __restrict__ b,
                             float* __restrict__ ws) {
    if (blockIdx.x == 0 && threadIdx.x == 0) write_params(w, r_dist, b, ws);
}

// 16 threads per node: int8 quantize + fp16 residual + per-head scaled norms.
__global__ __launch_bounds__(256) void convert_kernel(
    const float* __restrict__ h,
    const float* __restrict__ w,
    const float* __restrict__ r_dist,
    const float* __restrict__ b,
    float* __restrict__ ws,
    float* __restrict__ scales,
    float* __restrict__ nrm,
    uint2* __restrict__ q8,      // 16 uint2 per node
    uint4* __restrict__ r16,     // 16 uint4 per node
    int N) {
    if (blockIdx.x == 0 && threadIdx.x == 0) write_params(w, r_dist, b, ws);
    const int node = blockIdx.x * 16 + (threadIdx.x >> 4);
    const int sl   = threadIdx.x & 15;
    if (node >= N) return;

    const float4* hp = (const float4*)(h + (size_t)node * 128 + sl * 8);
    float4 v0 = hp[0], v1 = hp[1];
    float va[8] = {v0.x, v0.y, v0.z, v0.w, v1.x, v1.y, v1.z, v1.w};

    float m = 0.f;
    #pragma unroll
    for (int k = 0; k < 8; ++k) m = fmaxf(m, fabsf(va[k]));
    m = fmaxf(m, __shfl_xor(m, 1));
    m = fmaxf(m, __shfl_xor(m, 2));
    m = fmaxf(m, __shfl_xor(m, 4));
    m = fmaxf(m, __shfl_xor(m, 8));
    m = fmaxf(m, 1e-30f);

    const float s   = m * (1.0f / 127.0f);
    const float inv = 127.0f / m;

    int q[8];
    #pragma unroll
    for (int k = 0; k < 8; ++k) q[k] = (int)rintf(va[k] * inv);

    uint2 qp;
    qp.x = (q[0] & 255) | ((q[1] & 255) << 8) | ((q[2] & 255) << 16) | ((q[3] & 255) << 24);
    qp.y = (q[4] & 255) | ((q[5] & 255) << 8) | ((q[6] & 255) << 16) | ((q[7] & 255) << 24);
    q8[(size_t)node * 16 + sl] = qp;

    // per-head scaled norm: head = sl>>1 (adjacent lanes share a head)
    int n2 = SDOT4(qp.x, qp.x, 0); n2 = SDOT4(qp.y, qp.y, n2);
    int n2h = n2 + __shfl_xor(n2, 1);
    if ((sl & 1) == 0) nrm[(size_t)node * 8 + (sl >> 1)] = s * s * (float)n2h;

    uint4 rp;
    __half2 x;
    x = __floats2half2_rn(va[0] - s * q[0], va[1] - s * q[1]); rp.x = *(unsigned*)&x;
    x = __floats2half2_rn(va[2] - s * q[2], va[3] - s * q[3]); rp.y = *(unsigned*)&x;
    x = __floats2half2_rn(va[4] - s * q[4], va[5] - s * q[5]); rp.z = *(unsigned*)&x;
    x = __floats2half2_rn(va[6] - s * q[6], va[7] - s * q[7]); rp.w = *(unsigned*)&x;
    r16[(size_t)node * 16 + sl] = rp;

    if (sl == 0) scales[node] = s;
}

__device__ __forceinline__ float edge_dist32(float4 a, float4 c, float wgt) {
    float dx = c.x - a.x, dy = c.y - a.y, dz = c.z - a.z, dw = c.w - a.w;
    float ss = dx * dx + dy * dy + dz * dz + dw * dw;
    ss += __shfl_xor(ss, 1);
    ss += __shfl_xor(ss, 2);
    float t = sqrtf(ss) * wgt;
    t += __shfl_xor(t, 4);
    t += __shfl_xor(t, 8);
    t += __shfl_xor(t, 16);
    return t;
}

// Main: 8 lanes per edge (one head per lane), 4 edges per 32-group.
//   cross-dot = 4 SDOT4; self-norms precomputed; 3 shfl_xor reduce.
//   Near-boundary edges pushed to an LDS queue; refined after the main loop
//   with the q8 + fp16-residual reconstruction (R9's proven path).
__global__ __launch_bounds__(512) void score_kernel(
    const uint4* __restrict__ q84,
    const uint2* __restrict__ q82,
    const uint4* __restrict__ r16,
    const float* __restrict__ scales,
    const float* __restrict__ nrm,
    const int* __restrict__ src,
    const int* __restrict__ dst,
    const float* __restrict__ ws,
    float* __restrict__ out,
    int E) {
    __shared__ int s_src[EPB];
    __shared__ int s_dst[EPB];
    __shared__ int s_q[EPB];
    __shared__ int s_qn;
    __shared__ float s_w[8];
    __shared__ float s_m[32];
    __shared__ float s_b;

    const int t = threadIdx.x;
    if (t == 0) { s_qn = 0; s_b = ws[40]; }
    if (t < 8)  s_w[t] = ws[t];
    if (t < 32) s_m[t] = ws[8 + t];

    const long long base = (long long)blockIdx.x * EPB;
    if (base + EPB <= (long long)E) {
        ((int4*)s_src)[t] = ((const int4*)(src + base))[t];
        ((int4*)s_dst)[t] = ((const int4*)(dst + base))[t];
    } else {
        for (int i = t; i < EPB; i += 512) {
            long long e = base + i;
            s_src[i] = (e < (long long)E) ? src[e] : 0;
            s_dst[i] = (e < (long long)E) ? dst[e] : 0;
        }
    }
    __syncthreads();

    const int lane  = t & 31;
    const int h     = t & 7;          // head owned by this lane
    const int eq    = (t & 31) >> 3;  // edge slot within group (0..3)
    const int group = t >> 5;         // 16 groups
    const int shft  = t & 56;         // my edge's 8-bit field in the wave ballot

    const float wh = s_w[h];
    const float m0 = s_m[h], m1 = s_m[8 + h], m2 = s_m[16 + h], m3 = s_m[24 + h];
    const float bb = s_b;

    const int g0 = group * EPG;

    // prologue: first quad's loads
    int bi = g0 + eq;
    int sX = s_src[bi], dX = s_dst[bi];
    uint4 qs = q84[(size_t)sX * 8 + h];
    uint4 qd = q84[(size_t)dX * 8 + h];
    float sn = nrm[(size_t)sX * 8 + h];
    float dn = nrm[(size_t)dX * 8 + h];
    float ss = scales[sX], sd = scales[dX];

    for (int j = 0; j < EPG; j += 4) {
        // prefetch next quad
        const int jn  = (j + 4 < EPG) ? j + 4 : j;
        const int bin = g0 + jn + eq;
        const int sN = s_src[bin], dN = s_dst[bin];
        uint4 qsn = q84[(size_t)sN * 8 + h];
        uint4 qdn = q84[(size_t)dN * 8 + h];
        float snn = nrm[(size_t)sN * 8 + h];
        float dnn = nrm[(size_t)dN * 8 + h];
        float ssn = scales[sN], sdn = scales[dN];

        // ---- compute current ----
        int cx = SDOT4(qs.x, qd.x, 0);
        cx = SDOT4(qs.y, qd.y, cx);
        cx = SDOT4(qs.z, qd.z, cx);
        cx = SDOT4(qs.w, qd.w, cx);
        float part = sn + dn - 2.0f * ss * sd * (float)cx;
        float tt = sqrtf(fmaxf(part, 0.f)) * wh;
        tt += __shfl_xor(tt, 1);
        tt += __shfl_xor(tt, 2);
        tt += __shfl_xor(tt, 4);     // dist, identical in the edge's 8 lanes

        const int bcur = g0 + j + eq;
        const long long e = base + bcur;
        const float g0m = tt - m0, g1m = tt - m1, g2m = tt - m2, g3m = tt - m3;
        const bool near4 = (fabsf(g0m) < THETA) | (fabsf(g1m) < THETA) |
                           (fabsf(g2m) < THETA) | (fabsf(g3m) < THETA);
        const unsigned long long vote = __ballot(near4);
        const bool flag  = ((vote >> shft) & 0xFFULL) != 0ULL;
        const bool valid = e < (long long)E;
        if (flag) {
            if (h == 0 && valid) { int p = atomicAdd(&s_qn, 1); s_q[p] = bcur; }
        } else if (valid) {
            float* o = out + (size_t)e * 32 + h;
            __builtin_nontemporal_store(1.0f / (g0m * g0m + bb), o);
            __builtin_nontemporal_store(1.0f / (g1m * g1m + bb), o + 8);
            __builtin_nontemporal_store(1.0f / (g2m * g2m + bb), o + 16);
            __builtin_nontemporal_store(1.0f / (g3m * g3m + bb), o + 24);
        }

        sX = sN; dX = dN; qs = qsn; qd = qdn;
        sn = snn; dn = dnn; ss = ssn; sd = sdn;
    }

    __syncthreads();
    const int nq = s_qn;

    // ---- refine phase: 2 queued edges per 32-group per iter ----
    const int sl     = lane & 15;
    const int halfid = lane >> 4;
    const int hb     = halfid << 4;
    const float wmain = s_w[sl >> 1];
    const float m_c   = s_m[lane];

    for (int s0 = group * 2; s0 < nq; s0 += 32) {
        const int slot = s0 + halfid;
        const bool actB = (s0 + 1) < nq;
        const int biA = s_q[s0];
        const int biB = actB ? s_q[s0 + 1] : biA;
        const int bie = halfid ? biB : biA;
        const int sR = s_src[bie], dR = s_dst[bie];

        uint2 aq = q82[(size_t)sR * 16 + sl];
        uint2 bq = q82[(size_t)dR * 16 + sl];
        uint4 ar = r16[(size_t)sR * 16 + sl];
        uint4 br = r16[(size_t)dR * 16 + sl];
        float sc = (sl < 2) ? scales[sl ? dR : sR] : 0.f;
        const float ssc = __shfl(sc, hb + 0, 32);
        const float sdc = __shfl(sc, hb + 1, 32);

        const __half2* rsp = (const __half2*)&ar;
        const __half2* rdp = (const __half2*)&br;
        float acc = 0.f;
        #pragma unroll
        for (int k = 0; k < 8; ++k) {
            const unsigned qsw = (k < 4) ? aq.x : aq.y;
            const unsigned qdw = (k < 4) ? bq.x : bq.y;
            const int qsk = (int)(signed char)(qsw >> (8 * (k & 3)));
            const int qdk = (int)(signed char)(qdw >> (8 * (k & 3)));
            float2 rsf = __half22float2(rsp[k >> 1]);
            float2 rdf = __half22float2(rdp[k >> 1]);
            const float rsk = (k & 1) ? rsf.y : rsf.x;
            const float rdk = (k & 1) ? rdf.y : rdf.x;
            const float d = (ssc * qsk + rsk) - (sdc * qdk + rdk);
            acc += d * d;
        }
        acc += __shfl_xor(acc, 1);
        float ttr = sqrtf(acc) * wmain;
        ttr += __shfl_xor(ttr, 2);
        ttr += __shfl_xor(ttr, 4);
        ttr += __shfl_xor(ttr, 8);

        const float distA = __shfl(ttr, 0, 32);
        const float distB = __shfl(ttr, 16, 32);
        const float mA = distA - m_c;
        const float mB = distB - m_c;
        __builtin_nontemporal_store(1.0f / (mA * mA + bb),
                                    out + (size_t)(base + biA) * 32 + lane);
        if (actB)
            __builtin_nontemporal_store(1.0f / (mB * mB + bb),
                                        out + (size_t)(base + biB) * 32 + lane);
    }
}

// fallback: pure-f32 direct path (proven R1)
__global__ __launch_bounds__(256) void score_kernel_f32(
    const float* __restrict__ h,
    const int* __restrict__ src,
    const int* __restrict__ dst,
    const float* __restrict__ ws,
    float* __restrict__ out,
    int E) {
    __shared__ float s_w[8];
    __shared__ float s_m[32];
    __shared__ float s_b;
    const int t = threadIdx.x;
    if (t < 8)  s_w[t] = ws[t];
    if (t < 32) s_m[t] = ws[8 + t];
    if (t == 0) s_b = ws[40];
    __syncthreads();
    const int lane32 = t & 31;
    const int group  = t >> 5;
    const int gid    = blockIdx.x * 8 + group;
    const int stride = gridDim.x * 8;
    const float wgt  = s_w[lane32 >> 2];
    const float m_c  = s_m[lane32];
    const float bb   = s_b;
    for (int e = gid; e < E; e += stride) {
        const int si = src[e], di = dst[e];
        float4 a = ((const float4*)(h + (size_t)si * 128))[lane32];
        float4 c = ((const float4*)(h + (size_t)di * 128))[lane32];
        float tt = edge_dist32(a, c, wgt);
        float dm = tt - m_c;
        __builtin_nontemporal_store(1.0f / (dm * dm + bb),
                                    out + (size_t)e * 32 + lane32);
    }
}

extern "C" void kernel_launch(void* const* d_in, const int* in_sizes, int n_in,
                              void* d_out, int out_size, void* d_ws, size_t ws_size,
                              hipStream_t stream) {
    const float* h      = (const float*)d_in[0];
    const float* w      = (const float*)d_in[1];
    const float* r_dist = (const float*)d_in[2];
    const float* b      = (const float*)d_in[3];
    const int*   src    = (const int*)d_in[4];
    const int*   dst    = (const int*)d_in[5];
    float* out = (float*)d_out;
    float* ws  = (float*)d_ws;
    const int E = in_sizes[4];
    const int N = in_sizes[0] / 128;

    const size_t off_scales = 4096;
    const size_t off_nrm = (off_scales + (size_t)N * 4 + 255) & ~(size_t)255;
    const size_t off_q8  = (off_nrm + (size_t)N * 32 + 255) & ~(size_t)255;
    const size_t off_r16 = off_q8 + (size_t)N * 128;
    const size_t need    = off_r16 + (size_t)N * 256;

    if (ws_size >= need) {
        float* scales = (float*)((char*)d_ws + off_scales);
        float* nrm    = (float*)((char*)d_ws + off_nrm);
        uint2* q8     = (uint2*)((char*)d_ws + off_q8);
        uint4* r16    = (uint4*)((char*)d_ws + off_r16);
        const int cvt_blocks = (N + 15) / 16;
        const int nblocks = (E + EPB - 1) / EPB;
        convert_kernel<<<cvt_blocks, 256, 0, stream>>>(h, w, r_dist, b, ws,
                                                       scales, nrm, q8, r16, N);
        score_kernel<<<nblocks, 512, 0, stream>>>((const uint4*)q8, q8, r16,
                                                  scales, nrm, src, dst, ws,
                                                  out, E);
    } else {
        param_kernel<<<1, 64, 0, stream>>>(w, r_dist, b, ws);
        score_kernel_f32<<<2048, 256, 0, stream>>>(h, src, dst, ws, out, E);
    }
}

// Round 12
// 217.918 us; speedup vs baseline: 1.1018x; 1.1018x over previous
//
#include <hip/hip_runtime.h>
#include <hip/hip_fp16.h>

#define EPSC  1e-4f
#define THETA 0.05f
#define EPB   2048   // edges per block (512 thr = 16 groups x 128 edges)
#define EPG   128    // edges per 32-lane group

#if defined(__has_builtin)
#  if __has_builtin(__builtin_amdgcn_sdot4)
#    define SDOT4(a, b, c) __builtin_amdgcn_sdot4((int)(a), (int)(b), (c), false)
#  endif
#endif
#ifndef SDOT4
static __device__ __forceinline__ int sdot4_sw(unsigned a, unsigned b, int c) {
    #pragma unroll
    for (int k = 0; k < 4; ++k) {
        int ai = (int)(signed char)(a >> (8 * k));
        int bi = (int)(signed char)(b >> (8 * k));
        c += ai * bi;
    }
    return c;
}
#  define SDOT4(a, b, c) sdot4_sw((a), (b), (c))
#endif

// ws layout:
//   float[0..7] softmax(w), float[8..39] m, float[40] b
//   off_scales: scales f32[N]
//   off_nrm:    nrm    f32[N][8]  (= s^2 * sum q^2 per head)
//   off_q8:     q8     N x 128 B  (int8, per-node scale)
//   off_r16:    r16    N x 256 B  (fp16 residual h - s*q)   <- refine MUST be
//                                    near-exact (dist err <=1e-5); plain fp16
//                                    refine failed R11 with absmax 2944.

__device__ __forceinline__ void write_params(const float* w, const float* r_dist,
                                             const float* b, float* ws) {
    float wm = w[0];
    #pragma unroll
    for (int i = 1; i < 8; ++i) wm = fmaxf(wm, w[i]);
    float e[8]; float s = 0.f;
    #pragma unroll
    for (int i = 0; i < 8; ++i) { e[i] = __expf(w[i] - wm); s += e[i]; }
    float inv = 1.0f / s;
    #pragma unroll
    for (int i = 0; i < 8; ++i) ws[i] = e[i] * inv;
    float acc = 0.f;
    for (int c = 0; c < 32; ++c) {
        acc += fabsf(r_dist[c] + EPSC) + EPSC;
        ws[8 + c] = fmaxf(acc, 0.f);
    }
    ws[40] = b[0];
}

__global__ void param_kernel(const float* __restrict__ w,
                             const float* __restrict__ r_dist,
                             const float* __restrict__ b,
                             float* __restrict__ ws) {
    if (blockIdx.x == 0 && threadIdx.x == 0) write_params(w, r_dist, b, ws);
}

// 16 threads per node: int8 quantize + fp16 residual + per-head scaled norms.
__global__ __launch_bounds__(256) void convert_kernel(
    const float* __restrict__ h,
    const float* __restrict__ w,
    const float* __restrict__ r_dist,
    const float* __restrict__ b,
    float* __restrict__ ws,
    float* __restrict__ scales,
    float* __restrict__ nrm,
    uint2* __restrict__ q8,      // 16 uint2 per node
    uint4* __restrict__ r16,     // 16 uint4 per node
    int N) {
    if (blockIdx.x == 0 && threadIdx.x == 0) write_params(w, r_dist, b, ws);
    const int node = blockIdx.x * 16 + (threadIdx.x >> 4);
    const int sl   = threadIdx.x & 15;
    if (node >= N) return;

    const float4* hp = (const float4*)(h + (size_t)node * 128 + sl * 8);
    float4 v0 = hp[0], v1 = hp[1];
    float va[8] = {v0.x, v0.y, v0.z, v0.w, v1.x, v1.y, v1.z, v1.w};

    float m = 0.f;
    #pragma unroll
    for (int k = 0; k < 8; ++k) m = fmaxf(m, fabsf(va[k]));
    m = fmaxf(m, __shfl_xor(m, 1));
    m = fmaxf(m, __shfl_xor(m, 2));
    m = fmaxf(m, __shfl_xor(m, 4));
    m = fmaxf(m, __shfl_xor(m, 8));
    m = fmaxf(m, 1e-30f);

    const float s   = m * (1.0f / 127.0f);
    const float inv = 127.0f / m;

    int q[8];
    #pragma unroll
    for (int k = 0; k < 8; ++k) q[k] = (int)rintf(va[k] * inv);

    uint2 qp;
    qp.x = (q[0] & 255) | ((q[1] & 255) << 8) | ((q[2] & 255) << 16) | ((q[3] & 255) << 24);
    qp.y = (q[4] & 255) | ((q[5] & 255) << 8) | ((q[6] & 255) << 16) | ((q[7] & 255) << 24);
    q8[(size_t)node * 16 + sl] = qp;

    // per-head scaled norm (head = sl>>1; adjacent lanes share a head)
    int n2 = SDOT4(qp.x, qp.x, 0); n2 = SDOT4(qp.y, qp.y, n2);
    const int n2h = n2 + __shfl_xor(n2, 1);
    if ((sl & 1) == 0) nrm[(size_t)node * 8 + (sl >> 1)] = s * s * (float)n2h;

    uint4 rp;
    __half2 x;
    x = __floats2half2_rn(va[0] - s * q[0], va[1] - s * q[1]); rp.x = *(unsigned*)&x;
    x = __floats2half2_rn(va[2] - s * q[2], va[3] - s * q[3]); rp.y = *(unsigned*)&x;
    x = __floats2half2_rn(va[4] - s * q[4], va[5] - s * q[5]); rp.z = *(unsigned*)&x;
    x = __floats2half2_rn(va[6] - s * q[6], va[7] - s * q[7]); rp.w = *(unsigned*)&x;
    r16[(size_t)node * 16 + sl] = rp;

    if (sl == 0) scales[node] = s;
}

__device__ __forceinline__ float edge_dist32(float4 a, float4 c, float wgt) {
    float dx = c.x - a.x, dy = c.y - a.y, dz = c.z - a.z, dw = c.w - a.w;
    float ss = dx * dx + dy * dy + dz * dz + dw * dw;
    ss += __shfl_xor(ss, 1);
    ss += __shfl_xor(ss, 2);
    float t = sqrtf(ss) * wgt;
    t += __shfl_xor(t, 4);
    t += __shfl_xor(t, 8);
    t += __shfl_xor(t, 16);
    return t;
}

// Two edges per 32-lane group (lanes 0-15 edge A, 16-31 edge B).
// Main pass: int8 cross-dot (2 SDOT4/lane) + precomputed per-head norms
//            (one dword/lane: lane sl loads head sl>>1 of src if sl even,
//             dst if sl odd; pair shfl_xor(1) gives sn+dn).
// Refine (margin < THETA): q8 (in regs) + fp16-residual reconstruction —
//            R9's proven near-exact path (absmax 516).
__global__ __launch_bounds__(512) void score_kernel(
    const uint2* __restrict__ q8,
    const uint4* __restrict__ r16,
    const float* __restrict__ scales,
    const float* __restrict__ nrm,
    const int* __restrict__ src,
    const int* __restrict__ dst,
    const float* __restrict__ ws,
    float* __restrict__ out,
    int E) {
    __shared__ int s_src[EPB];
    __shared__ int s_dst[EPB];
    __shared__ float s_w[8];
    __shared__ float s_m[32];
    __shared__ float s_b;

    const int t = threadIdx.x;
    if (t < 8)  s_w[t] = ws[t];
    if (t < 32) s_m[t] = ws[8 + t];
    if (t == 0) s_b = ws[40];

    const long long base = (long long)blockIdx.x * EPB;
    if (base + EPB <= (long long)E) {
        ((int4*)s_src)[t] = ((const int4*)(src + base))[t];
        ((int4*)s_dst)[t] = ((const int4*)(dst + base))[t];
    } else {
        for (int i = t; i < EPB; i += 512) {
            long long e = base + i;
            s_src[i] = (e < (long long)E) ? src[e] : 0;
            s_dst[i] = (e < (long long)E) ? dst[e] : 0;
        }
    }
    __syncthreads();

    const int lane   = t & 31;        // lane within 32-group
    const int sl     = lane & 15;     // sub-lane within 16-half
    const int halfid = lane >> 4;     // 0 = edge A, 1 = edge B
    const int hb     = halfid << 4;   // half base (0 or 16)
    const int group  = t >> 5;        // 16 groups per block
    const int gsh    = t & 32;        // group's shift in the wave ballot
    const int headp  = sl >> 1;       // head owned by this lane pair

    const float wmain = s_w[headp];
    const float m_c   = s_m[lane];
    const float bb    = s_b;

    const int g0 = group * EPG;

    // prologue: pair 0 loads
    int sX = s_src[g0 + halfid];
    int dX = s_dst[g0 + halfid];
    uint2 qs = q8[(size_t)sX * 16 + sl];
    uint2 qd = q8[(size_t)dX * 16 + sl];
    float nv = nrm[(size_t)((sl & 1) ? dX : sX) * 8 + headp];
    float sc0 = (sl < 2) ? scales[sl == 0 ? sX : dX] : 0.f;

    for (int j = 0; j < EPG; j += 2) {
        // issue next pair's gathers
        const int jn = (j + 2 < EPG) ? j + 2 : j;
        const int sN = s_src[g0 + jn + halfid];
        const int dN = s_dst[g0 + jn + halfid];
        uint2 qsn = q8[(size_t)sN * 16 + sl];
        uint2 qdn = q8[(size_t)dN * 16 + sl];
        float nvn = nrm[(size_t)((sl & 1) ? dN : sN) * 8 + headp];
        float scn = (sl < 2) ? scales[sl == 0 ? sN : dN] : 0.f;

        // ---- compute current pair ----
        const float ssc = __shfl(sc0, hb + 0, 32);
        const float sdc = __shfl(sc0, hb + 1, 32);

        int cx = SDOT4(qs.x, qd.x, 0);
        cx = SDOT4(qs.y, qd.y, cx);
        float cxp = (float)cx;
        cxp += __shfl_xor(cxp, 1);                 // per-head cross dot (exact)
        const float nvs = nv + __shfl_xor(nv, 1);  // sn + dn for this head

        float part = nvs - 2.0f * ssc * sdc * cxp;
        float tt = sqrtf(fmaxf(part, 0.f)) * wmain;
        tt += __shfl_xor(tt, 2);                   // sum heads
        tt += __shfl_xor(tt, 4);
        tt += __shfl_xor(tt, 8);

        float distA = __shfl(tt, 0, 32);
        float distB = __shfl(tt, 16, 32);

        const bool nearA = fabsf(distA - m_c) < THETA;
        const bool nearB = fabsf(distB - m_c) < THETA;
        const unsigned long long bA = __ballot(nearA);
        const unsigned long long bB = __ballot(nearB);
        const bool refA = ((bA >> gsh) & 0xffffffffULL) != 0ULL;
        const bool refB = ((bB >> gsh) & 0xffffffffULL) != 0ULL;

        if (refA || refB) {                        // group-uniform branch
            const bool doref = halfid ? refB : refA;
            float ttr = 0.f;
            if (doref) {                           // half-uniform
                uint4 rs = r16[(size_t)sX * 16 + sl];
                uint4 rd = r16[(size_t)dX * 16 + sl];
                const __half2* rsp = (const __half2*)&rs;
                const __half2* rdp = (const __half2*)&rd;
                float acc = 0.f;
                #pragma unroll
                for (int k = 0; k < 8; ++k) {
                    const unsigned qsw = (k < 4) ? qs.x : qs.y;
                    const unsigned qdw = (k < 4) ? qd.x : qd.y;
                    const int qsk = (int)(signed char)(qsw >> (8 * (k & 3)));
                    const int qdk = (int)(signed char)(qdw >> (8 * (k & 3)));
                    float2 rsf = __half22float2(rsp[k >> 1]);
                    float2 rdf = __half22float2(rdp[k >> 1]);
                    const float rsk = (k & 1) ? rsf.y : rsf.x;
                    const float rdk = (k & 1) ? rdf.y : rdf.x;
                    const float d = (ssc * qsk + rsk) - (sdc * qdk + rdk);
                    acc += d * d;
                }
                acc += __shfl_xor(acc, 1);
                ttr = sqrtf(acc) * wmain;
                ttr += __shfl_xor(ttr, 2);
                ttr += __shfl_xor(ttr, 4);
                ttr += __shfl_xor(ttr, 8);
            }
            if (refA) distA = __shfl(ttr, 0, 32);
            if (refB) distB = __shfl(ttr, 16, 32);
        }

        const float mA = distA - m_c;
        const float mB = distB - m_c;
        const long long eA = base + g0 + j;
        if (eA < (long long)E)
            __builtin_nontemporal_store(1.0f / (mA * mA + bb),
                                        out + (size_t)eA * 32 + lane);
        if (eA + 1 < (long long)E)
            __builtin_nontemporal_store(1.0f / (mB * mB + bb),
                                        out + (size_t)(eA + 1) * 32 + lane);

        // rotate pipeline
        sX = sN; dX = dN; qs = qsn; qd = qdn; nv = nvn; sc0 = scn;
    }
}

// fallback: pure-f32 direct path (proven R1)
__global__ __launch_bounds__(256) void score_kernel_f32(
    const float* __restrict__ h,
    const int* __restrict__ src,
    const int* __restrict__ dst,
    const float* __restrict__ ws,
    float* __restrict__ out,
    int E) {
    __shared__ float s_w[8];
    __shared__ float s_m[32];
    __shared__ float s_b;
    const int t = threadIdx.x;
    if (t < 8)  s_w[t] = ws[t];
    if (t < 32) s_m[t] = ws[8 + t];
    if (t == 0) s_b = ws[40];
    __syncthreads();
    const int lane32 = t & 31;
    const int group  = t >> 5;
    const int gid    = blockIdx.x * 8 + group;
    const int stride = gridDim.x * 8;
    const float wgt  = s_w[lane32 >> 2];
    const float m_c  = s_m[lane32];
    const float bb   = s_b;
    for (int e = gid; e < E; e += stride) {
        const int si = src[e], di = dst[e];
        float4 a = ((const float4*)(h + (size_t)si * 128))[lane32];
        float4 c = ((const float4*)(h + (size_t)di * 128))[lane32];
        float tt = edge_dist32(a, c, wgt);
        float dm = tt - m_c;
        __builtin_nontemporal_store(1.0f / (dm * dm + bb),
                                    out + (size_t)e * 32 + lane32);
    }
}

extern "C" void kernel_launch(void* const* d_in, const int* in_sizes, int n_in,
                              void* d_out, int out_size, void* d_ws, size_t ws_size,
                              hipStream_t stream) {
    const float* h      = (const float*)d_in[0];
    const float* w      = (const float*)d_in[1];
    const float* r_dist = (const float*)d_in[2];
    const float* b      = (const float*)d_in[3];
    const int*   src    = (const int*)d_in[4];
    const int*   dst    = (const int*)d_in[5];
    float* out = (float*)d_out;
    float* ws  = (float*)d_ws;
    const int E = in_sizes[4];
    const int N = in_sizes[0] / 128;

    const size_t off_scales = 4096;
    const size_t off_nrm = (off_scales + (size_t)N * 4 + 255) & ~(size_t)255;
    const size_t off_q8  = (off_nrm + (size_t)N * 32 + 255) & ~(size_t)255;
    const size_t off_r16 = off_q8 + (size_t)N * 128;
    const size_t need    = off_r16 + (size_t)N * 256;

    if (ws_size >= need) {
        float* scales = (float*)((char*)d_ws + off_scales);
        float* nrm    = (float*)((char*)d_ws + off_nrm);
        uint2* q8     = (uint2*)((char*)d_ws + off_q8);
        uint4* r16    = (uint4*)((char*)d_ws + off_r16);
        const int cvt_blocks = (N + 15) / 16;
        const int nblocks = (E + EPB - 1) / EPB;
        convert_kernel<<<cvt_blocks, 256, 0, stream>>>(h, w, r_dist, b, ws,
                                                       scales, nrm, q8, r16, N);
        score_kernel<<<nblocks, 512, 0, stream>>>(q8, r16, scales, nrm,
                                                  src, dst, ws, out, E);
    } else {
        param_kernel<<<1, 64, 0, stream>>>(w, r_dist, b, ws);
        score_kernel_f32<<<2048, 256, 0, stream>>>(h, src, dst, ws, out, E);
    }
}

// Round 13
// 189.429 us; speedup vs baseline: 1.2675x; 1.1504x over previous
//
#include <hip/hip_runtime.h>
#include <hip/hip_fp16.h>

#define EPSC  1e-4f
#define THETA 0.05f
#define EPB   2048   // edges per block (512 thr = 16 groups x 128 edges)
#define EPG   128    // edges per 32-lane group

#if defined(__has_builtin)
#  if __has_builtin(__builtin_amdgcn_sdot4)
#    define SDOT4(a, b, c) __builtin_amdgcn_sdot4((int)(a), (int)(b), (c), false)
#  endif
#endif
#ifndef SDOT4
static __device__ __forceinline__ int sdot4_sw(unsigned a, unsigned b, int c) {
    #pragma unroll
    for (int k = 0; k < 4; ++k) {
        int ai = (int)(signed char)(a >> (8 * k));
        int bi = (int)(signed char)(b >> (8 * k));
        c += ai * bi;
    }
    return c;
}
#  define SDOT4(a, b, c) sdot4_sw((a), (b), (c))
#endif

// ws layout:
//   float[0..7] softmax(w), float[8..39] m, float[40] b
//   off_scales: scales f32[N]
//   off_q8:     q8     N x 128 B (int8, per-node scale)
//   off_r16:    r16    N x 256 B (fp16 residual h - s*q)
// NOTE (R11 lesson): refine path must be near-exact (dist err <=1e-5).
// NOTE (R12 lesson): do not replace in-register SDOT4 norms with table loads.

__device__ __forceinline__ void write_params(const float* w, const float* r_dist,
                                             const float* b, float* ws) {
    float wm = w[0];
    #pragma unroll
    for (int i = 1; i < 8; ++i) wm = fmaxf(wm, w[i]);
    float e[8]; float s = 0.f;
    #pragma unroll
    for (int i = 0; i < 8; ++i) { e[i] = __expf(w[i] - wm); s += e[i]; }
    float inv = 1.0f / s;
    #pragma unroll
    for (int i = 0; i < 8; ++i) ws[i] = e[i] * inv;
    float acc = 0.f;
    for (int c = 0; c < 32; ++c) {
        acc += fabsf(r_dist[c] + EPSC) + EPSC;
        ws[8 + c] = fmaxf(acc, 0.f);
    }
    ws[40] = b[0];
}

__global__ void param_kernel(const float* __restrict__ w,
                             const float* __restrict__ r_dist,
                             const float* __restrict__ b,
                             float* __restrict__ ws) {
    if (blockIdx.x == 0 && threadIdx.x == 0) write_params(w, r_dist, b, ws);
}

// 16 threads per node: quantize to int8 with per-node scale + fp16 residual.
__global__ __launch_bounds__(256) void convert_kernel(
    const float* __restrict__ h,
    const float* __restrict__ w,
    const float* __restrict__ r_dist,
    const float* __restrict__ b,
    float* __restrict__ ws,
    float* __restrict__ scales,
    uint2* __restrict__ q8,      // 16 uint2 per node
    uint4* __restrict__ r16,     // 16 uint4 per node
    int N) {
    if (blockIdx.x == 0 && threadIdx.x == 0) write_params(w, r_dist, b, ws);
    const int node = blockIdx.x * 16 + (threadIdx.x >> 4);
    const int sl   = threadIdx.x & 15;
    if (node >= N) return;

    const float4* hp = (const float4*)(h + (size_t)node * 128 + sl * 8);
    float4 v0 = hp[0], v1 = hp[1];
    float va[8] = {v0.x, v0.y, v0.z, v0.w, v1.x, v1.y, v1.z, v1.w};

    float m = 0.f;
    #pragma unroll
    for (int k = 0; k < 8; ++k) m = fmaxf(m, fabsf(va[k]));
    m = fmaxf(m, __shfl_xor(m, 1));
    m = fmaxf(m, __shfl_xor(m, 2));
    m = fmaxf(m, __shfl_xor(m, 4));
    m = fmaxf(m, __shfl_xor(m, 8));
    m = fmaxf(m, 1e-30f);

    const float s   = m * (1.0f / 127.0f);
    const float inv = 127.0f / m;

    int q[8];
    #pragma unroll
    for (int k = 0; k < 8; ++k) q[k] = (int)rintf(va[k] * inv);

    uint2 qp;
    qp.x = (q[0] & 255) | ((q[1] & 255) << 8) | ((q[2] & 255) << 16) | ((q[3] & 255) << 24);
    qp.y = (q[4] & 255) | ((q[5] & 255) << 8) | ((q[6] & 255) << 16) | ((q[7] & 255) << 24);
    q8[(size_t)node * 16 + sl] = qp;

    uint4 rp;
    __half2 x;
    x = __floats2half2_rn(va[0] - s * q[0], va[1] - s * q[1]); rp.x = *(unsigned*)&x;
    x = __floats2half2_rn(va[2] - s * q[2], va[3] - s * q[3]); rp.y = *(unsigned*)&x;
    x = __floats2half2_rn(va[4] - s * q[4], va[5] - s * q[5]); rp.z = *(unsigned*)&x;
    x = __floats2half2_rn(va[6] - s * q[6], va[7] - s * q[7]); rp.w = *(unsigned*)&x;
    r16[(size_t)node * 16 + sl] = rp;

    if (sl == 0) scales[node] = s;
}

__device__ __forceinline__ float edge_dist32(float4 a, float4 c, float wgt) {
    float dx = c.x - a.x, dy = c.y - a.y, dz = c.z - a.z, dw = c.w - a.w;
    float ss = dx * dx + dy * dy + dz * dz + dw * dw;
    ss += __shfl_xor(ss, 1);
    ss += __shfl_xor(ss, 2);
    float t = sqrtf(ss) * wgt;
    t += __shfl_xor(t, 4);
    t += __shfl_xor(t, 8);
    t += __shfl_xor(t, 16);
    return t;
}

// Two edges per 32-lane group (lanes 0-15 edge A, 16-31 edge B).
// Main pass: int8 gather (one 128B line/node), exact integer dot via SDOT4
// (self-norms recomputed in-register — zero traffic).
// Refine (margin < THETA): fp16 residual gather, near-exact reconstruction.
__global__ __launch_bounds__(512) void score_kernel(
    const uint2* __restrict__ q8,
    const uint4* __restrict__ r16,
    const float* __restrict__ scales,
    const int* __restrict__ src,
    const int* __restrict__ dst,
    const float* __restrict__ ws,
    float* __restrict__ out,
    int E) {
    __shared__ int s_src[EPB];
    __shared__ int s_dst[EPB];
    __shared__ float s_w[8];
    __shared__ float s_m[32];
    __shared__ float s_b;

    const int t = threadIdx.x;
    if (t < 8)  s_w[t] = ws[t];
    if (t < 32) s_m[t] = ws[8 + t];
    if (t == 0) s_b = ws[40];

    const long long base = (long long)blockIdx.x * EPB;
    if (base + EPB <= (long long)E) {
        ((int4*)s_src)[t] = ((const int4*)(src + base))[t];
        ((int4*)s_dst)[t] = ((const int4*)(dst + base))[t];
    } else {
        for (int i = t; i < EPB; i += 512) {
            long long e = base + i;
            s_src[i] = (e < (long long)E) ? src[e] : 0;
            s_dst[i] = (e < (long long)E) ? dst[e] : 0;
        }
    }
    __syncthreads();

    const int lane   = t & 31;        // lane within 32-group
    const int sl     = lane & 15;     // sub-lane within 16-half
    const int halfid = lane >> 4;     // 0 = edge A, 1 = edge B
    const int hb     = halfid << 4;   // half base (0 or 16)
    const int group  = t >> 5;        // 16 groups per block
    const int gsh    = t & 32;        // group's shift in the wave ballot

    const float wmain = s_w[sl >> 1]; // 2 lanes per head
    const float m_c   = s_m[lane];
    const float bb    = s_b;

    const int g0 = group * EPG;

    // prologue: pair 0 loads
    int sX = s_src[g0 + halfid];
    int dX = s_dst[g0 + halfid];
    uint2 qs = q8[(size_t)sX * 16 + sl];
    uint2 qd = q8[(size_t)dX * 16 + sl];
    float sc0 = (sl < 2) ? scales[sl == 0 ? sX : dX] : 0.f;

    for (int j = 0; j < EPG; j += 2) {
        // issue next pair's gathers
        const int jn = (j + 2 < EPG) ? j + 2 : j;
        const int sN = s_src[g0 + jn + halfid];
        const int dN = s_dst[g0 + jn + halfid];
        uint2 qsn = q8[(size_t)sN * 16 + sl];
        uint2 qdn = q8[(size_t)dN * 16 + sl];
        float scn = (sl < 2) ? scales[sl == 0 ? sN : dN] : 0.f;

        // ---- compute current pair ----
        const float ssc = __shfl(sc0, hb + 0, 32);   // src scale of my half's edge
        const float sdc = __shfl(sc0, hb + 1, 32);   // dst scale

        int cx = SDOT4(qs.x, qd.x, 0); cx = SDOT4(qs.y, qd.y, cx);
        int sn2 = SDOT4(qs.x, qs.x, 0); sn2 = SDOT4(qs.y, qs.y, sn2);
        int dn2 = SDOT4(qd.x, qd.x, 0); dn2 = SDOT4(qd.y, qd.y, dn2);

        float part = ssc * ssc * (float)sn2 + sdc * sdc * (float)dn2
                   - 2.0f * ssc * sdc * (float)cx;
        part += __shfl_xor(part, 1);                 // per-head ||diff||^2
        float tt = sqrtf(fmaxf(part, 0.f)) * wmain;
        tt += __shfl_xor(tt, 2);                     // sum heads
        tt += __shfl_xor(tt, 4);
        tt += __shfl_xor(tt, 8);

        float distA = __shfl(tt, 0, 32);
        float distB = __shfl(tt, 16, 32);

        const bool nearA = fabsf(distA - m_c) < THETA;
        const bool nearB = fabsf(distB - m_c) < THETA;
        const unsigned long long bA = __ballot(nearA);
        const unsigned long long bB = __ballot(nearB);
        const bool refA = ((bA >> gsh) & 0xffffffffULL) != 0ULL;
        const bool refB = ((bB >> gsh) & 0xffffffffULL) != 0ULL;

        if (refA || refB) {
            const bool doref = halfid ? refB : refA;
            float ttr = 0.f;
            if (doref) {
                uint4 rs = r16[(size_t)sX * 16 + sl];
                uint4 rd = r16[(size_t)dX * 16 + sl];
                const __half2* rsp = (const __half2*)&rs;
                const __half2* rdp = (const __half2*)&rd;
                float acc = 0.f;
                #pragma unroll
                for (int k = 0; k < 8; ++k) {
                    const unsigned qsw = (k < 4) ? qs.x : qs.y;
                    const unsigned qdw = (k < 4) ? qd.x : qd.y;
                    const int qsk = (int)(signed char)(qsw >> (8 * (k & 3)));
                    const int qdk = (int)(signed char)(qdw >> (8 * (k & 3)));
                    float2 rsf = __half22float2(rsp[k >> 1]);
                    float2 rdf = __half22float2(rdp[k >> 1]);
                    const float rsk = (k & 1) ? rsf.y : rsf.x;
                    const float rdk = (k & 1) ? rdf.y : rdf.x;
                    const float d = (ssc * qsk + rsk) - (sdc * qdk + rdk);
                    acc += d * d;
                }
                acc += __shfl_xor(acc, 1);
                ttr = sqrtf(acc) * wmain;
                ttr += __shfl_xor(ttr, 2);
                ttr += __shfl_xor(ttr, 4);
                ttr += __shfl_xor(ttr, 8);
            }
            if (refA) distA = __shfl(ttr, 0, 32);
            if (refB) distB = __shfl(ttr, 16, 32);
        }

        const float mA = distA - m_c;
        const float mB = distB - m_c;
        const long long eA = base + g0 + j;
        if (eA < (long long)E)
            __builtin_nontemporal_store(1.0f / (mA * mA + bb),
                                        out + (size_t)eA * 32 + lane);
        if (eA + 1 < (long long)E)
            __builtin_nontemporal_store(1.0f / (mB * mB + bb),
                                        out + (size_t)(eA + 1) * 32 + lane);

        // rotate pipeline
        sX = sN; dX = dN; qs = qsn; qd = qdn; sc0 = scn;
    }
}

// fallback: pure-f32 direct path (proven R1)
__global__ __launch_bounds__(256) void score_kernel_f32(
    const float* __restrict__ h,
    const int* __restrict__ src,
    const int* __restrict__ dst,
    const float* __restrict__ ws,
    float* __restrict__ out,
    int E) {
    __shared__ float s_w[8];
    __shared__ float s_m[32];
    __shared__ float s_b;
    const int t = threadIdx.x;
    if (t < 8)  s_w[t] = ws[t];
    if (t < 32) s_m[t] = ws[8 + t];
    if (t == 0) s_b = ws[40];
    __syncthreads();
    const int lane32 = t & 31;
    const int group  = t >> 5;
    const int gid    = blockIdx.x * 8 + group;
    const int stride = gridDim.x * 8;
    const float wgt  = s_w[lane32 >> 2];
    const float m_c  = s_m[lane32];
    const float bb   = s_b;
    for (int e = gid; e < E; e += stride) {
        const int si = src[e], di = dst[e];
        float4 a = ((const float4*)(h + (size_t)si * 128))[lane32];
        float4 c = ((const float4*)(h + (size_t)di * 128))[lane32];
        float tt = edge_dist32(a, c, wgt);
        float dm = tt - m_c;
        __builtin_nontemporal_store(1.0f / (dm * dm + bb),
                                    out + (size_t)e * 32 + lane32);
    }
}

extern "C" void kernel_launch(void* const* d_in, const int* in_sizes, int n_in,
                              void* d_out, int out_size, void* d_ws, size_t ws_size,
                              hipStream_t stream) {
    const float* h      = (const float*)d_in[0];
    const float* w      = (const float*)d_in[1];
    const float* r_dist = (const float*)d_in[2];
    const float* b      = (const float*)d_in[3];
    const int*   src    = (const int*)d_in[4];
    const int*   dst    = (const int*)d_in[5];
    float* out = (float*)d_out;
    float* ws  = (float*)d_ws;
    const int E = in_sizes[4];
    const int N = in_sizes[0] / 128;

    const size_t off_scales = 4096;
    const size_t off_q8  = (off_scales + (size_t)N * 4 + 255) & ~(size_t)255;
    const size_t off_r16 = off_q8 + (size_t)N * 128;
    const size_t need    = off_r16 + (size_t)N * 256;

    if (ws_size >= need) {
        float* scales = (float*)((char*)d_ws + off_scales);
        uint2* q8     = (uint2*)((char*)d_ws + off_q8);
        uint4* r16    = (uint4*)((char*)d_ws + off_r16);
        const int cvt_blocks = (N + 15) / 16;
        const int nblocks = (E + EPB - 1) / EPB;
        convert_kernel<<<cvt_blocks, 256, 0, stream>>>(h, w, r_dist, b, ws,
                                                       scales, q8, r16, N);
        score_kernel<<<nblocks, 512, 0, stream>>>(q8, r16, scales, src, dst,
                                                  ws, out, E);
    } else {
        param_kernel<<<1, 64, 0, stream>>>(w, r_dist, b, ws);
        score_kernel_f32<<<2048, 256, 0, stream>>>(h, src, dst, ws, out, E);
    }
}